// Round 1
// baseline (187.122 us; speedup 1.0000x reference)
//
#include <hip/hip_runtime.h>

#define POOL 7
#define NUM_ROIS 600
#define IMG_H 96
#define IMG_W 96
#define IMG_C 1024

// One block per (roi, py, px) output pixel: 600*49 = 29400 blocks.
// 256 threads x float4 = 1024 channels, fully coalesced 16B/lane loads/stores.
// ROI/bilinear math is wave-uniform (no divergence); channels innermost (NHWC)
// so the 4 corner-pixel reads and the store are perfectly contiguous.
__global__ __launch_bounds__(256) void roi_pool_kernel(
    const float* __restrict__ img,      // (96, 96, 1024)
    const int* __restrict__ rois,       // (600, 4) as (x, y, w, h)
    float* __restrict__ out)            // (600, 7, 7, 1024)
{
    const int b   = blockIdx.x;         // roi*49 + py*7 + px
    const int roi = b / (POOL * POOL);
    const int p   = b - roi * (POOL * POOL);
    const int py  = p / POOL;
    const int px  = p - py * POOL;

    const int4 r = *(const int4*)(rois + roi * 4);
    const int x = r.x;
    const int y = r.y;
    const int w = max(r.z, 1);
    const int h = max(r.w, 1);

    // TF1 resize (align_corners=False): src = dst * (in/out). Match JAX f32
    // op order exactly: scale = float(h)/7.0f, then multiply by out index.
    const float in_y = (float)py * ((float)h / (float)POOL);
    const float in_x = (float)px * ((float)w / (float)POOL);
    const int y0 = (int)floorf(in_y);
    const int x0 = (int)floorf(in_x);
    const int y1 = min(y0 + 1, h - 1);
    const int x1 = min(x0 + 1, w - 1);
    const float fy = in_y - (float)y0;
    const float fx = in_x - (float)x0;
    const float gy = 1.0f - fy;
    const float gx = 1.0f - fx;

    // crop-local -> image coords, clamped
    const int R0 = min(max(y + y0, 0), IMG_H - 1);
    const int R1 = min(max(y + y1, 0), IMG_H - 1);
    const int C0 = min(max(x + x0, 0), IMG_W - 1);
    const int C1 = min(max(x + x1, 0), IMG_W - 1);

    const int ch = threadIdx.x * 4;
    const float4 v00 = *(const float4*)(img + (size_t)(R0 * IMG_W + C0) * IMG_C + ch);
    const float4 v01 = *(const float4*)(img + (size_t)(R0 * IMG_W + C1) * IMG_C + ch);
    const float4 v10 = *(const float4*)(img + (size_t)(R1 * IMG_W + C0) * IMG_C + ch);
    const float4 v11 = *(const float4*)(img + (size_t)(R1 * IMG_W + C1) * IMG_C + ch);

    float4 o;
    o.x = (v00.x * gx + v01.x * fx) * gy + (v10.x * gx + v11.x * fx) * fy;
    o.y = (v00.y * gx + v01.y * fx) * gy + (v10.y * gx + v11.y * fx) * fy;
    o.z = (v00.z * gx + v01.z * fx) * gy + (v10.z * gx + v11.z * fx) * fy;
    o.w = (v00.w * gx + v01.w * fx) * gy + (v10.w * gx + v11.w * fx) * fy;

    *(float4*)(out + (size_t)b * IMG_C + ch) = o;
}

extern "C" void kernel_launch(void* const* d_in, const int* in_sizes, int n_in,
                              void* d_out, int out_size, void* d_ws, size_t ws_size,
                              hipStream_t stream) {
    const float* img  = (const float*)d_in[0];
    const int*   rois = (const int*)d_in[1];
    float*       out  = (float*)d_out;

    const int nblocks = NUM_ROIS * POOL * POOL;  // 29400
    roi_pool_kernel<<<nblocks, 256, 0, stream>>>(img, rois, out);
}

// Round 3
// 181.806 us; speedup vs baseline: 1.0292x; 1.0292x over previous
//
#include <hip/hip_runtime.h>

#define POOL 7
#define NUM_ROIS 600
#define IMG_H 96
#define IMG_W 96
#define IMG_C 1024

// Native clang vector type — required by __builtin_nontemporal_store
// (HIP_vector_type float4 is rejected) and gives identical codegen for math.
typedef float v4f __attribute__((ext_vector_type(4)));

// Block per (roi, py): 600*7 = 4200 blocks, 256 threads (4 waves).
// Each block loops px=0..6; the duplicated corner-column reads between
// consecutive px become L1/L2-temporal on one CU instead of cross-XCD
// refetches. Output is streamed with nontemporal stores so the 117.6 MB
// write stream does not evict the image working set from the per-XCD L2s.
// blockIdx swizzle: the 7 blocks of one roi share blockIdx%8 so round-robin
// dispatch lands them on the same XCD (locality heuristic only).
__global__ __launch_bounds__(256) void roi_pool_kernel(
    const float* __restrict__ img,      // (96, 96, 1024)
    const int* __restrict__ rois,       // (600, 4) as (x, y, w, h)
    float* __restrict__ out)            // (600, 7, 7, 1024)
{
    const int b   = blockIdx.x;         // 0..4199
    const int xcd = b & 7;
    const int j   = b >> 3;             // 0..524
    const int py  = j % POOL;
    const int k   = j / POOL;           // 0..74
    const int roi = k * 8 + xcd;        // 0..599 (600 = 75*8 exactly)

    const int4 r = *(const int4*)(rois + roi * 4);
    const int x = r.x;
    const int y = r.y;
    const int w = max(r.z, 1);
    const int h = max(r.w, 1);

    // TF1 resize semantics, f32 op order identical to the JAX reference:
    // scale = float(dim)/7.0f computed once, then index * scale.
    const float sy = (float)h / (float)POOL;
    const float sx = (float)w / (float)POOL;

    const float in_y = (float)py * sy;
    const int y0 = (int)floorf(in_y);
    const int y1 = min(y0 + 1, h - 1);
    const float fy = in_y - (float)y0;
    const float gy = 1.0f - fy;
    const int R0 = min(max(y + y0, 0), IMG_H - 1);
    const int R1 = min(max(y + y1, 0), IMG_H - 1);

    const int ch = threadIdx.x * 4;
    const float* row0 = img + (size_t)R0 * IMG_W * IMG_C + ch;
    const float* row1 = img + (size_t)R1 * IMG_W * IMG_C + ch;
    float* outp = out + ((size_t)roi * POOL * POOL + (size_t)py * POOL) * IMG_C + ch;

#pragma unroll
    for (int px = 0; px < POOL; ++px) {
        const float in_x = (float)px * sx;
        const int x0 = (int)floorf(in_x);
        const int x1 = min(x0 + 1, w - 1);
        const float fx = in_x - (float)x0;
        const float gx = 1.0f - fx;
        const int C0 = min(max(x + x0, 0), IMG_W - 1);
        const int C1 = min(max(x + x1, 0), IMG_W - 1);

        const v4f v00 = *(const v4f*)(row0 + (size_t)C0 * IMG_C);
        const v4f v01 = *(const v4f*)(row0 + (size_t)C1 * IMG_C);
        const v4f v10 = *(const v4f*)(row1 + (size_t)C0 * IMG_C);
        const v4f v11 = *(const v4f*)(row1 + (size_t)C1 * IMG_C);

        const v4f o = (v00 * gx + v01 * fx) * gy + (v10 * gx + v11 * fx) * fy;

        __builtin_nontemporal_store(o, (v4f*)(outp + (size_t)px * IMG_C));
    }
}

extern "C" void kernel_launch(void* const* d_in, const int* in_sizes, int n_in,
                              void* d_out, int out_size, void* d_ws, size_t ws_size,
                              hipStream_t stream) {
    const float* img  = (const float*)d_in[0];
    const int*   rois = (const int*)d_in[1];
    float*       out  = (float*)d_out;

    const int nblocks = NUM_ROIS * POOL;  // 4200
    roi_pool_kernel<<<nblocks, 256, 0, stream>>>(img, rois, out);
}

// Round 4
// 175.352 us; speedup vs baseline: 1.0671x; 1.0368x over previous
//
#include <hip/hip_runtime.h>

#define POOL 7
#define NUM_ROIS 600
#define IMG_H 96
#define IMG_W 96
#define IMG_C 1024

typedef float v4f __attribute__((ext_vector_type(4)));

// ---------------------------------------------------------------------------
// Pass 1: counting-sort ROI indices by Morton code of their (x>>3, y>>3) bin.
// Spatially neighboring ROIs become adjacent in perm[] -> concurrent blocks
// on an XCD read overlapping image rows -> cross-ROI reuse becomes
// L2-capturable instead of thrashing (concurrent set was ~29 MB vs 4 MB L2).
// Single block, runs in ~2-3 us; recomputed every call (d_ws is re-poisoned).
// ---------------------------------------------------------------------------
__global__ __launch_bounds__(640) void bin_rois_kernel(
    const int* __restrict__ rois, int* __restrict__ perm)
{
    __shared__ int cnt[64];
    __shared__ int base[64];
    const int t = threadIdx.x;
    if (t < 64) cnt[t] = 0;
    __syncthreads();

    int mybin = 0;
    if (t < NUM_ROIS) {
        const int x = rois[t * 4 + 0];
        const int y = rois[t * 4 + 1];
        const int bx = min(max(x, 0), 63) >> 3;   // 0..7
        const int by = min(max(y, 0), 63) >> 3;   // 0..7
        // 3-bit Morton interleave for 2D locality
        mybin = (bx & 1) | ((by & 1) << 1) | ((bx & 2) << 1) |
                ((by & 2) << 2) | ((bx & 4) << 2) | ((by & 4) << 3);
        atomicAdd(&cnt[mybin], 1);
    }
    __syncthreads();
    if (t == 0) {
        int s = 0;
        for (int i = 0; i < 64; ++i) { base[i] = s; s += cnt[i]; cnt[i] = 0; }
    }
    __syncthreads();
    if (t < NUM_ROIS) {
        const int pos = base[mybin] + atomicAdd(&cnt[mybin], 1);
        perm[pos] = t;
    }
}

// ---------------------------------------------------------------------------
// Pass 2: block per (sorted_pos, py): 600*7 = 4200 blocks, 256 threads.
// XCD chunking: blockIdx&7 selects a contiguous chunk of 75 sorted positions,
// so (under round-robin block->XCD dispatch) each XCD works one spatial
// cluster of ROIs. Output written with nontemporal stores (write stream never
// re-read; keep L2 for image lines).
// ---------------------------------------------------------------------------
__global__ __launch_bounds__(256) void roi_pool_kernel(
    const float* __restrict__ img,      // (96, 96, 1024)
    const int* __restrict__ rois,       // (600, 4) as (x, y, w, h)
    const int* __restrict__ perm,       // (600,) spatial-sorted roi indices
    float* __restrict__ out)            // (600, 7, 7, 1024)
{
    const int g   = blockIdx.x;         // 0..4199
    const int xcd = g & 7;
    const int i   = g >> 3;             // 0..524
    const int py  = i % POOL;
    const int loc = i / POOL;           // 0..74 within this XCD's chunk
    const int pos = xcd * (NUM_ROIS / 8) + loc;   // contiguous sorted chunk
    const int roi = perm[pos];

    const int4 r = *(const int4*)(rois + roi * 4);
    const int x = r.x;
    const int y = r.y;
    const int w = max(r.z, 1);
    const int h = max(r.w, 1);

    // TF1 resize semantics, f32 op order identical to the JAX reference.
    const float sy = (float)h / (float)POOL;
    const float sx = (float)w / (float)POOL;

    const float in_y = (float)py * sy;
    const int y0 = (int)floorf(in_y);
    const int y1 = min(y0 + 1, h - 1);
    const float fy = in_y - (float)y0;
    const float gy = 1.0f - fy;
    const int R0 = min(max(y + y0, 0), IMG_H - 1);
    const int R1 = min(max(y + y1, 0), IMG_H - 1);

    const int ch = threadIdx.x * 4;
    const float* row0 = img + (size_t)R0 * IMG_W * IMG_C + ch;
    const float* row1 = img + (size_t)R1 * IMG_W * IMG_C + ch;
    float* outp = out + ((size_t)roi * POOL * POOL + (size_t)py * POOL) * IMG_C + ch;

#pragma unroll
    for (int px = 0; px < POOL; ++px) {
        const float in_x = (float)px * sx;
        const int x0 = (int)floorf(in_x);
        const int x1 = min(x0 + 1, w - 1);
        const float fx = in_x - (float)x0;
        const float gx = 1.0f - fx;
        const int C0 = min(max(x + x0, 0), IMG_W - 1);
        const int C1 = min(max(x + x1, 0), IMG_W - 1);

        const v4f v00 = *(const v4f*)(row0 + (size_t)C0 * IMG_C);
        const v4f v01 = *(const v4f*)(row0 + (size_t)C1 * IMG_C);
        const v4f v10 = *(const v4f*)(row1 + (size_t)C0 * IMG_C);
        const v4f v11 = *(const v4f*)(row1 + (size_t)C1 * IMG_C);

        const v4f o = (v00 * gx + v01 * fx) * gy + (v10 * gx + v11 * fx) * fy;

        __builtin_nontemporal_store(o, (v4f*)(outp + (size_t)px * IMG_C));
    }
}

extern "C" void kernel_launch(void* const* d_in, const int* in_sizes, int n_in,
                              void* d_out, int out_size, void* d_ws, size_t ws_size,
                              hipStream_t stream) {
    const float* img  = (const float*)d_in[0];
    const int*   rois = (const int*)d_in[1];
    float*       out  = (float*)d_out;
    int*         perm = (int*)d_ws;      // 600 ints of scratch

    bin_rois_kernel<<<1, 640, 0, stream>>>(rois, perm);
    roi_pool_kernel<<<NUM_ROIS * POOL, 256, 0, stream>>>(img, rois, perm, out);
}

// Round 5
// 169.914 us; speedup vs baseline: 1.1013x; 1.0320x over previous
//
#include <hip/hip_runtime.h>

#define POOL 7
#define NUM_ROIS 600
#define IMG_H 96
#define IMG_W 96
#define IMG_C 1024

typedef float v4f __attribute__((ext_vector_type(4)));

// ---------------------------------------------------------------------------
// Pass 1: counting-sort ROI indices by Morton code of their (x>>3, y>>3) bin.
// Spatially neighboring ROIs become adjacent in perm[] -> concurrent blocks
// on an XCD read overlapping image rows (cross-ROI L2 reuse). ~3 us.
// ---------------------------------------------------------------------------
__global__ __launch_bounds__(640) void bin_rois_kernel(
    const int* __restrict__ rois, int* __restrict__ perm)
{
    __shared__ int cnt[64];
    __shared__ int base[64];
    const int t = threadIdx.x;
    if (t < 64) cnt[t] = 0;
    __syncthreads();

    int mybin = 0;
    if (t < NUM_ROIS) {
        const int x = rois[t * 4 + 0];
        const int y = rois[t * 4 + 1];
        const int bx = min(max(x, 0), 63) >> 3;   // 0..7
        const int by = min(max(y, 0), 63) >> 3;   // 0..7
        mybin = (bx & 1) | ((by & 1) << 1) | ((bx & 2) << 1) |
                ((by & 2) << 2) | ((bx & 4) << 2) | ((by & 4) << 3);
        atomicAdd(&cnt[mybin], 1);
    }
    __syncthreads();
    if (t == 0) {
        int s = 0;
        for (int i = 0; i < 64; ++i) { base[i] = s; s += cnt[i]; cnt[i] = 0; }
    }
    __syncthreads();
    if (t < NUM_ROIS) {
        const int pos = base[mybin] + atomicAdd(&cnt[mybin], 1);
        perm[pos] = t;
    }
}

// ---------------------------------------------------------------------------
// Pass 2: block per (sorted_pos, py), 1024 threads as (256 ch-lanes, 4 px
// streams). Each y-stream does px = ty and px = ty+4 (ty==3 skips the 2nd).
// Rationale vs R4 (serial px loop): the 7 px positions now run CONCURRENTLY
// on one CU -> 7x the in-flight loads per (roi,py) (latency hiding) while
// keeping the shared corner-column L1 locality that the serial loop had.
// VGPR ~24 -> 2 blocks/CU = 32 waves/CU (full occupancy).
// ---------------------------------------------------------------------------
__global__ __launch_bounds__(1024) void roi_pool_kernel(
    const float* __restrict__ img,      // (96, 96, 1024)
    const int* __restrict__ rois,       // (600, 4) as (x, y, w, h)
    const int* __restrict__ perm,       // (600,) spatial-sorted roi indices
    float* __restrict__ out)            // (600, 7, 7, 1024)
{
    const int g   = blockIdx.x;         // 0..4199
    const int xcd = g & 7;
    const int i   = g >> 3;             // 0..524
    const int py  = i % POOL;
    const int loc = i / POOL;           // 0..74 within this XCD's chunk
    const int pos = xcd * (NUM_ROIS / 8) + loc;
    const int roi = perm[pos];

    const int4 r = *(const int4*)(rois + roi * 4);
    const int x = r.x;
    const int y = r.y;
    const int w = max(r.z, 1);
    const int h = max(r.w, 1);

    // TF1 resize semantics, f32 op order identical to the JAX reference.
    const float sy = (float)h / (float)POOL;
    const float sx = (float)w / (float)POOL;

    const float in_y = (float)py * sy;
    const int y0 = (int)floorf(in_y);
    const int y1 = min(y0 + 1, h - 1);
    const float fy = in_y - (float)y0;
    const float gy = 1.0f - fy;
    const int R0 = min(max(y + y0, 0), IMG_H - 1);
    const int R1 = min(max(y + y1, 0), IMG_H - 1);

    const int ch = threadIdx.x * 4;
    const float* row0 = img + (size_t)R0 * IMG_W * IMG_C + ch;
    const float* row1 = img + (size_t)R1 * IMG_W * IMG_C + ch;
    float* outp = out + ((size_t)roi * POOL * POOL + (size_t)py * POOL) * IMG_C + ch;

#pragma unroll
    for (int k = 0; k < 2; ++k) {
        const int px = threadIdx.y + k * 4;
        if (px < POOL) {
            const float in_x = (float)px * sx;
            const int x0 = (int)floorf(in_x);
            const int x1 = min(x0 + 1, w - 1);
            const float fx = in_x - (float)x0;
            const float gx = 1.0f - fx;
            const int C0 = min(max(x + x0, 0), IMG_W - 1);
            const int C1 = min(max(x + x1, 0), IMG_W - 1);

            const v4f v00 = *(const v4f*)(row0 + (size_t)C0 * IMG_C);
            const v4f v01 = *(const v4f*)(row0 + (size_t)C1 * IMG_C);
            const v4f v10 = *(const v4f*)(row1 + (size_t)C0 * IMG_C);
            const v4f v11 = *(const v4f*)(row1 + (size_t)C1 * IMG_C);

            const v4f o = (v00 * gx + v01 * fx) * gy + (v10 * gx + v11 * fx) * fy;

            __builtin_nontemporal_store(o, (v4f*)(outp + (size_t)px * IMG_C));
        }
    }
}

extern "C" void kernel_launch(void* const* d_in, const int* in_sizes, int n_in,
                              void* d_out, int out_size, void* d_ws, size_t ws_size,
                              hipStream_t stream) {
    const float* img  = (const float*)d_in[0];
    const int*   rois = (const int*)d_in[1];
    float*       out  = (float*)d_out;
    int*         perm = (int*)d_ws;      // 600 ints of scratch

    bin_rois_kernel<<<1, 640, 0, stream>>>(rois, perm);
    dim3 block(256, 4, 1);
    roi_pool_kernel<<<NUM_ROIS * POOL, block, 0, stream>>>(img, rois, perm, out);
}